// Round 6
// baseline (88.908 us; speedup 1.0000x reference)
//
#include <hip/hip_runtime.h>

#define T 128
#define L2E 1.4426950408889634f   // log2(e)
#define LN2F 0.6931471805599453f  // ln(2)

typedef _Float16 h2 __attribute__((ext_vector_type(2)));

// lane l <- lane l-1; lane 0 <- 0   (DPP wave_shr:1, bound_ctrl=0)
__device__ __forceinline__ float shr1(float x) {
    return __int_as_float(__builtin_amdgcn_update_dpp(
        0, __float_as_int(x), 0x138, 0xF, 0xF, true));
}

template <int CTRL>
__device__ __forceinline__ float dppmax(float x) {
    float t = __int_as_float(__builtin_amdgcn_update_dpp(
        __float_as_int(x), __float_as_int(x), CTRL, 0xF, 0xF, false));
    return fmaxf(x, t);
}

__device__ __forceinline__ float dot2(h2 x, float ybits, float acc) {
    return __builtin_amdgcn_fdot2(x, __builtin_bit_cast(h2, ybits), acc, false);
}

struct Pair { float4 ye; float se; float4 yo; float so; };

__launch_bounds__(256)
__global__ void sdtw_kernel(const float* __restrict__ X,
                            const float* __restrict__ Y,
                            float* __restrict__ out) {
    // Even array: h holds y-row j = 2h-126; odd array: j = 2h+1-126 (h in [0,195]).
    // Out-of-range j -> sentinel (y=0, s=-3e37 => E=0). float4 rows: lane-stride
    // 16B ds_read_b128 = conflict-free; s arrays lane-stride 4B = 2-way (free).
    __shared__ float4 EYs[4][196];
    __shared__ float  ESs[4][196];
    __shared__ float4 OYs[4][196];
    __shared__ float  OSs[4][196];
    const int lane = threadIdx.x & 63;
    const int w    = threadIdx.x >> 6;
    const int pair = blockIdx.x * 4 + w;   // 512 blocks * 4 waves = 2048 pairs
    const int a = pair >> 4;               // X index
    const int b = pair & 15;               // Y index

    const float4* eyw = EYs[w];
    const float*  esw = ESs[w];
    const float4* oyw = OYs[w];
    const float*  osw = OSs[w];

    // ---- stage Y[b]: y' = 2*L2E*y (f16 pairs), s = -L2E*|y|^2; sentinels ----
    {
        const float* ybase = Y + (size_t)b * T * 8;
        for (int idx = lane; idx < 392; idx += 64) {
            int P = idx & 1, h = idx >> 1;
            int j = 2 * h + P - 126;
            float4 pk; pk.x = 0.f; pk.y = 0.f; pk.z = 0.f; pk.w = 0.f;
            float sq = -3.0e37f;
            if (j >= 0 && j < T) {
                const float4* src = (const float4*)(ybase + j * 8);
                float4 y0 = src[0], y1 = src[1];
                float s = y0.x*y0.x + y0.y*y0.y + y0.z*y0.z + y0.w*y0.w
                        + y1.x*y1.x + y1.y*y1.y + y1.z*y1.z + y1.w*y1.w;
                const float c = 2.0f * L2E;
                h2 a0 = { (_Float16)(c*y0.x), (_Float16)(c*y0.y) };
                h2 a1 = { (_Float16)(c*y0.z), (_Float16)(c*y0.w) };
                h2 a2 = { (_Float16)(c*y1.x), (_Float16)(c*y1.y) };
                h2 a3 = { (_Float16)(c*y1.z), (_Float16)(c*y1.w) };
                pk.x = __builtin_bit_cast(float, a0);
                pk.y = __builtin_bit_cast(float, a1);
                pk.z = __builtin_bit_cast(float, a2);
                pk.w = __builtin_bit_cast(float, a3);
                sq = -L2E * s;
            }
            if (P) { OYs[w][h] = pk; OSs[w][h] = sq; }
            else   { EYs[w][h] = pk; ESs[w][h] = sq; }
        }
    }

    // ---- X rows 2l (even) and 2l+1 (odd) for this lane ----
    h2 xe0, xe1, xe2, xe3, xo0, xo1, xo2, xo3;
    float lsxe, lsxo;
    {
        const float* xb = X + ((size_t)a * T + 2 * lane) * 8;
        const float4* s0p = (const float4*)xb;
        float4 v0 = s0p[0], v1 = s0p[1], u0 = s0p[2], u1 = s0p[3];
        xe0 = h2{ (_Float16)v0.x, (_Float16)v0.y };
        xe1 = h2{ (_Float16)v0.z, (_Float16)v0.w };
        xe2 = h2{ (_Float16)v1.x, (_Float16)v1.y };
        xe3 = h2{ (_Float16)v1.z, (_Float16)v1.w };
        lsxe = -L2E * (v0.x*v0.x+v0.y*v0.y+v0.z*v0.z+v0.w*v0.w
                      +v1.x*v1.x+v1.y*v1.y+v1.z*v1.z+v1.w*v1.w);
        xo0 = h2{ (_Float16)u0.x, (_Float16)u0.y };
        xo1 = h2{ (_Float16)u0.z, (_Float16)u0.w };
        xo2 = h2{ (_Float16)u1.x, (_Float16)u1.y };
        xo3 = h2{ (_Float16)u1.z, (_Float16)u1.w };
        lsxo = -L2E * (u0.x*u0.x+u0.y*u0.y+u0.z*u0.z+u0.w*u0.w
                      +u1.x*u1.x+u1.y*u1.y+u1.z*u1.z+u1.w*u1.w);
    }

    __syncthreads();

    const int hb0 = 63 - lane;

    // even-cell row from O, odd-cell row from E (positions 1,3) or vice versa (2,4)
#define LD_OE(SET, HE, HO) { SET.ye = oyw[HE]; SET.se = osw[HE]; \
                             SET.yo = eyw[HO]; SET.so = esw[HO]; }
#define LD_EO(SET, HE, HO) { SET.ye = eyw[HE]; SET.se = esw[HE]; \
                             SET.yo = oyw[HO]; SET.so = osw[HO]; }

    // D-stage: rows -> E values (independent of recurrence; tree-shaped dots)
#define DSTAGE(EE, EO, SET) {                                \
    float t0 = dot2(xe0, SET.ye.x, lsxe);                    \
    float t1 = dot2(xe1, SET.ye.y, SET.se);                  \
    t0 = dot2(xe2, SET.ye.z, t0);                            \
    t1 = dot2(xe3, SET.ye.w, t1);                            \
    EE = __builtin_amdgcn_exp2f(t0 + t1);                    \
    float u0 = dot2(xo0, SET.yo.x, lsxo);                    \
    float u1 = dot2(xo1, SET.yo.y, SET.so);                  \
    u0 = dot2(xo2, SET.yo.z, u0);                            \
    u1 = dot2(xo3, SET.yo.w, u1);                            \
    EO = __builtin_amdgcn_exp2f(u0 + u1);                    \
}

    // R-stage: the only serial part (2 DPP + 6 VALU)
#define RSTAGE(PE1, PE2, PO1, PO2, EE, EO) {                 \
    float sB = shr1(PO1);                                    \
    float sA = shr1(PO2);                                    \
    float Se = EE * ((sA + sB) + PE1);                       \
    float So = EO * ((PE2 + PE1) + PO1);                     \
    PE2 = Se; PO2 = So;                                      \
}

#define RENORM() {                                                            \
    float mx = fmaxf(fmaxf(fe0, fe1), fmaxf(fo0, fo1));                       \
    mx = dppmax<0x111>(mx);  /* row_shr:1 */                                  \
    mx = dppmax<0x112>(mx);  /* row_shr:2 */                                  \
    mx = dppmax<0x114>(mx);  /* row_shr:4 */                                  \
    mx = dppmax<0x118>(mx);  /* row_shr:8 */                                  \
    int r0_ = __builtin_amdgcn_readlane(__float_as_int(mx), 15);              \
    int r1_ = __builtin_amdgcn_readlane(__float_as_int(mx), 31);              \
    int r2_ = __builtin_amdgcn_readlane(__float_as_int(mx), 47);              \
    int r3_ = __builtin_amdgcn_readlane(__float_as_int(mx), 63);              \
    int mb = max(max(r0_, r1_), max(r2_, r3_));                               \
    int e = ((mb >> 23) & 0xff) - 217;   /* renorm max to 2^90 */             \
    fe0 = ldexpf(fe0, -e); fe1 = ldexpf(fe1, -e);                             \
    fo0 = ldexpf(fo0, -e); fo1 = ldexpf(fo1, -e);                             \
    off -= e;                                                                 \
}

    // ---- prologue: preload row sets for bodies p=1..4; E(1); p=0 cell ----
    Pair S1, S2, S3, S4;
    LD_OE(S1, hb0,     hb0);       // rows for p=1
    LD_EO(S2, hb0 + 1, hb0);       // p=2
    LD_OE(S3, hb0 + 1, hb0 + 1);   // p=3
    LD_EO(S4, hb0 + 2, hb0 + 1);   // p=4

    float fe0 = 0.f, fo0 = 0.f, fo1 = 0.f, fe1;
    int off = 90;
    {   // p = 0: cell (0,0) on lane 0 (sentinels zero all other lanes)
        float4 yv = eyw[hb0];
        float  sv = esw[hb0];
        float t0 = dot2(xe0, yv.x, lsxe);
        float t1 = dot2(xe1, yv.y, sv);
        t0 = dot2(xe2, yv.z, t0);
        t1 = dot2(xe3, yv.w, t1);
        fe1 = __builtin_amdgcn_exp2f(t0 + t1) * 0x1p90f;
    }
    float EeA, EoA, EeB, EoB;
    DSTAGE(EeA, EoA, S1);          // E for p=1

    // ---- main loop: 63 groups of 4 bodies (p = 1..252) ----
    int hb = hb0;
    for (int g = 0; g < 63; ++g) {
        // pos1, p=4g+1
        RSTAGE(fe1, fe0, fo1, fo0, EeA, EoA);
        DSTAGE(EeB, EoB, S2);                 // E(p+1)
        LD_OE(S1, hb + 2, hb + 2);            // rows(p+4)
        // pos2, p=4g+2
        RSTAGE(fe0, fe1, fo0, fo1, EeB, EoB);
        DSTAGE(EeA, EoA, S3);
        LD_EO(S2, hb + 3, hb + 2);
        // pos3, p=4g+3
        RSTAGE(fe1, fe0, fo1, fo0, EeA, EoA);
        DSTAGE(EeB, EoB, S4);
        LD_OE(S3, hb + 3, hb + 3);
        // pos4, p=4g+4
        RSTAGE(fe0, fe1, fo0, fo1, EeB, EoB);
        DSTAGE(EeA, EoA, S1);                 // E(4g+5) from just-reloaded S1
        LD_EO(S4, hb + 4, hb + 3);
        RENORM();
        hb += 2;
    }

    // ---- tail: p = 253, 254 ----
    RSTAGE(fe1, fe0, fo1, fo0, EeA, EoA);     // p=253
    DSTAGE(EeB, EoB, S2);                     // E(254) (S2 = rows(254))
    RSTAGE(fe0, fe1, fo0, fo1, EeB, EoB);     // p=254 -> new So in fo1

    // final cell (127,127) = odd row of lane 63: R = (off - log2(S)) * ln2
    if (lane == 63)
        out[pair] = ((float)off - __builtin_amdgcn_logf(fo1)) * LN2F;
}

extern "C" void kernel_launch(void* const* d_in, const int* in_sizes, int n_in,
                              void* d_out, int out_size, void* d_ws, size_t ws_size,
                              hipStream_t stream) {
    const float* X = (const float*)d_in[0];   // (128,128,8) f32
    const float* Y = (const float*)d_in[1];   // (16,128,8) f32
    float* out = (float*)d_out;               // (128,16) f32
    sdtw_kernel<<<512, 256, 0, stream>>>(X, Y, out);
}

// Round 7
// 87.797 us; speedup vs baseline: 1.0127x; 1.0127x over previous
//
#include <hip/hip_runtime.h>

#define T 128
#define L2E 1.4426950408889634f   // log2(e)
#define LN2F 0.6931471805599453f  // ln(2)
#define SENT -3.0e37f

typedef _Float16 h2 __attribute__((ext_vector_type(2)));

// lane l <- lane l-1; lane 0 <- 0   (DPP wave_shr:1, bound_ctrl=0) -- verified r3-r6
__device__ __forceinline__ float shr1(float x) {
    return __int_as_float(__builtin_amdgcn_update_dpp(
        0, __float_as_int(x), 0x138, 0xF, 0xF, true));
}

// conveyor step: lane l <- chain[l-1]; lane 0 <- fresh (old operand retained)
__device__ __forceinline__ float mrg(float fresh, float chain) {
    return __int_as_float(__builtin_amdgcn_update_dpp(
        __float_as_int(fresh), __float_as_int(chain), 0x138, 0xF, 0xF, false));
}

template <int CTRL>
__device__ __forceinline__ float dppmax(float x) {
    float t = __int_as_float(__builtin_amdgcn_update_dpp(
        __float_as_int(x), __float_as_int(x), CTRL, 0xF, 0xF, false));
    return fmaxf(x, t);
}

__device__ __forceinline__ float dot2(h2 x, float ybits, float acc) {
    return __builtin_amdgcn_fdot2(x, __builtin_bit_cast(h2, ybits), acc, false);
}

struct Row { float4 y; float s; };

__launch_bounds__(256)
__global__ void sdtw_kernel(const float* __restrict__ X,
                            const float* __restrict__ Y,
                            float* __restrict__ out) {
    // Per wave: 256 rows x 8 dwords (32 B): [4x f16-pair y', f32 s, 3 pad].
    // Rows 0..127 = real y-rows; 128..255 = sentinel (y=0, s=-3e37 => E=0).
    // Main loop reads are wave-uniform broadcasts only (conflict-free).
    __shared__ __align__(16) float lds[4][2048];
    const int lane = threadIdx.x & 63;
    const int w    = threadIdx.x >> 6;
    const int pair = blockIdx.x * 4 + w;   // 512 blocks * 4 waves = 2048 pairs
    const int a = pair >> 4;               // X index
    const int b = pair & 15;               // Y index

    float* yw = lds[w];

    // ---- stage: 4 rows per lane ----
    {
        const float* ybase = Y + (size_t)b * T * 8;
        for (int k = 0; k < 4; ++k) {
            int r = lane + 64 * k;
            float4 pk; pk.x = 0.f; pk.y = 0.f; pk.z = 0.f; pk.w = 0.f;
            float sq = SENT;
            if (r < T) {
                const float4* src = (const float4*)(ybase + r * 8);
                float4 y0 = src[0], y1 = src[1];
                float s = y0.x*y0.x + y0.y*y0.y + y0.z*y0.z + y0.w*y0.w
                        + y1.x*y1.x + y1.y*y1.y + y1.z*y1.z + y1.w*y1.w;
                const float c = 2.0f * L2E;
                h2 a0 = { (_Float16)(c*y0.x), (_Float16)(c*y0.y) };
                h2 a1 = { (_Float16)(c*y0.z), (_Float16)(c*y0.w) };
                h2 a2 = { (_Float16)(c*y1.x), (_Float16)(c*y1.y) };
                h2 a3 = { (_Float16)(c*y1.z), (_Float16)(c*y1.w) };
                pk.x = __builtin_bit_cast(float, a0);
                pk.y = __builtin_bit_cast(float, a1);
                pk.z = __builtin_bit_cast(float, a2);
                pk.w = __builtin_bit_cast(float, a3);
                sq = -L2E * s;
            }
            float* dst = yw + r * 8;
            *(float4*)dst = pk;
            float4 t; t.x = sq; t.y = 0.f; t.z = 0.f; t.w = 0.f;
            *(float4*)(dst + 4) = t;
        }
    }

    // ---- X rows 2l (even cell) and 2l+1 (odd cell) for this lane ----
    h2 xe0, xe1, xe2, xe3, xo0, xo1, xo2, xo3;
    float lsxe, lsxo;
    {
        const float* xb = X + ((size_t)a * T + 2 * lane) * 8;
        const float4* s0p = (const float4*)xb;
        float4 v0 = s0p[0], v1 = s0p[1], u0 = s0p[2], u1 = s0p[3];
        xe0 = h2{ (_Float16)v0.x, (_Float16)v0.y };
        xe1 = h2{ (_Float16)v0.z, (_Float16)v0.w };
        xe2 = h2{ (_Float16)v1.x, (_Float16)v1.y };
        xe3 = h2{ (_Float16)v1.z, (_Float16)v1.w };
        lsxe = -L2E * (v0.x*v0.x+v0.y*v0.y+v0.z*v0.z+v0.w*v0.w
                      +v1.x*v1.x+v1.y*v1.y+v1.z*v1.z+v1.w*v1.w);
        xo0 = h2{ (_Float16)u0.x, (_Float16)u0.y };
        xo1 = h2{ (_Float16)u0.z, (_Float16)u0.w };
        xo2 = h2{ (_Float16)u1.x, (_Float16)u1.y };
        xo3 = h2{ (_Float16)u1.z, (_Float16)u1.w };
        lsxo = -L2E * (u0.x*u0.x+u0.y*u0.y+u0.z*u0.z+u0.w*u0.w
                      +u1.x*u1.x+u1.y*u1.y+u1.z*u1.z+u1.w*u1.w);
    }

    __syncthreads();

    // ---- conveyor registers: A = even-source at p=0, B = odd-source ----
    Row A, B;
    {
        float4 r0y = *(const float4*)(yw);     // row 0 broadcast
        float  r0s = yw[4];
        bool l0 = (lane == 0);
        A.y.x = l0 ? r0y.x : 0.f;
        A.y.y = l0 ? r0y.y : 0.f;
        A.y.z = l0 ? r0y.z : 0.f;
        A.y.w = l0 ? r0y.w : 0.f;
        A.s   = l0 ? r0s   : SENT;
        B.y.x = 0.f; B.y.y = 0.f; B.y.z = 0.f; B.y.w = 0.f;
        B.s   = SENT;
    }

    // ---- p = 0: even cell (0,0) on lane 0 (sentinels zero the rest) ----
    float fe0 = 0.f, fo0 = 0.f, fo1 = 0.f, fe1;
    int off = 90;
    {
        float t0 = dot2(xe0, A.y.x, lsxe);
        float t1 = dot2(xe1, A.y.y, A.s);
        t0 = dot2(xe2, A.y.z, t0);
        t1 = dot2(xe3, A.y.w, t1);
        fe1 = __builtin_amdgcn_exp2f(t0 + t1) * 0x1p90f;
    }
    {   // p=0 update: inject row 1 into B (B becomes even-source for p=1)
        float4 fy = *(const float4*)(yw + 8);
        float  fs = yw[12];
        B.y.x = mrg(fy.x, B.y.x); B.y.y = mrg(fy.y, B.y.y);
        B.y.z = mrg(fy.z, B.y.z); B.y.w = mrg(fy.w, B.y.w);
        B.s   = mrg(fs,   B.s);
    }

    // BODY: PE1/PO1 = p-1 state, PE2/PO2 = p-2 state (overwritten).
    // RE = even-cell row regs, RO = odd-cell row regs; after compute, RO is
    // conveyor-stepped with fresh row F (row p+1) -> becomes RE of body p+1.
#define BODY(PE1, PE2, PO1, PO2, RE, RO, F) {           \
    float t0 = dot2(xe0, RE.y.x, lsxe);                 \
    float t1 = dot2(xe1, RE.y.y, RE.s);                 \
    t0 = dot2(xe2, RE.y.z, t0);                         \
    t1 = dot2(xe3, RE.y.w, t1);                         \
    float Ee = __builtin_amdgcn_exp2f(t0 + t1);         \
    float u0 = dot2(xo0, RO.y.x, lsxo);                 \
    float u1 = dot2(xo1, RO.y.y, RO.s);                 \
    u0 = dot2(xo2, RO.y.z, u0);                         \
    u1 = dot2(xo3, RO.y.w, u1);                         \
    float Eo = __builtin_amdgcn_exp2f(u0 + u1);         \
    float sB = shr1(PO1);                               \
    float sA = shr1(PO2);                               \
    float Se = Ee * ((sA + sB) + PE1);                  \
    float So = Eo * ((PE2 + PE1) + PO1);                \
    PE2 = Se; PO2 = So;                                 \
    RO.y.x = mrg(F.y.x, RO.y.x);                        \
    RO.y.y = mrg(F.y.y, RO.y.y);                        \
    RO.y.z = mrg(F.y.z, RO.y.z);                        \
    RO.y.w = mrg(F.y.w, RO.y.w);                        \
    RO.s   = mrg(F.s,   RO.s);                          \
}

#define RENORM() {                                                            \
    float mx = fmaxf(fmaxf(fe0, fe1), fmaxf(fo0, fo1));                       \
    mx = dppmax<0x111>(mx);  /* row_shr:1 */                                  \
    mx = dppmax<0x112>(mx);  /* row_shr:2 */                                  \
    mx = dppmax<0x114>(mx);  /* row_shr:4 */                                  \
    mx = dppmax<0x118>(mx);  /* row_shr:8 */                                  \
    int r0_ = __builtin_amdgcn_readlane(__float_as_int(mx), 15);              \
    int r1_ = __builtin_amdgcn_readlane(__float_as_int(mx), 31);              \
    int r2_ = __builtin_amdgcn_readlane(__float_as_int(mx), 47);              \
    int r3_ = __builtin_amdgcn_readlane(__float_as_int(mx), 63);              \
    int mb = max(max(r0_, r1_), max(r2_, r3_));                               \
    int e = ((mb >> 23) & 0xff) - 217;   /* renorm max to 2^90 */             \
    fe0 = ldexpf(fe0, -e); fe1 = ldexpf(fe1, -e);                             \
    fo0 = ldexpf(fo0, -e); fo1 = ldexpf(fo1, -e);                             \
    off -= e;                                                                 \
}

#define LOADF(F, OFS) { F.y = *(const float4*)(gb + (OFS)); F.s = gb[(OFS) + 4]; }

    // ---- main: 31 groups of 8 bodies (p = 1..248), renorm per group ----
    int rb = 16;   // dword offset of row 2 (first injected row of group 0)
    for (int g = 0; g < 31; ++g) {
        const float* gb = yw + rb;
        Row F0, F1, F2, F3, F4, F5, F6, F7;
        LOADF(F0, 0);  LOADF(F1, 8);  LOADF(F2, 16); LOADF(F3, 24);
        LOADF(F4, 32); LOADF(F5, 40); LOADF(F6, 48); LOADF(F7, 56);
        __builtin_amdgcn_sched_barrier(0);   // keep broadcasts hoisted here
        BODY(fe1, fe0, fo1, fo0, B, A, F0);  // p = 8g+1
        BODY(fe0, fe1, fo0, fo1, A, B, F1);
        BODY(fe1, fe0, fo1, fo0, B, A, F2);
        BODY(fe0, fe1, fo0, fo1, A, B, F3);
        BODY(fe1, fe0, fo1, fo0, B, A, F4);
        BODY(fe0, fe1, fo0, fo1, A, B, F5);
        BODY(fe1, fe0, fo1, fo0, B, A, F6);
        BODY(fe0, fe1, fo0, fo1, A, B, F7);  // p = 8g+8
        RENORM();
        rb += 64;
    }

    // ---- tail: p = 249..254 (rows 250..255, all sentinel region) ----
    {
        const float* gb = yw + rb;   // rb = 2000 = row 250
        Row F0, F1, F2, F3, F4, F5;
        LOADF(F0, 0);  LOADF(F1, 8);  LOADF(F2, 16);
        LOADF(F3, 24); LOADF(F4, 32); LOADF(F5, 40);
        __builtin_amdgcn_sched_barrier(0);
        BODY(fe1, fe0, fo1, fo0, B, A, F0);  // p = 249
        BODY(fe0, fe1, fo0, fo1, A, B, F1);
        BODY(fe1, fe0, fo1, fo0, B, A, F2);
        BODY(fe0, fe1, fo0, fo1, A, B, F3);
        BODY(fe1, fe0, fo1, fo0, B, A, F4);  // p = 253
        BODY(fe0, fe1, fo0, fo1, A, B, F5);  // p = 254 -> new So in fo1
    }

    // final cell (127,127) = odd row of lane 63: R = (off - log2(S)) * ln2
    if (lane == 63)
        out[pair] = ((float)off - __builtin_amdgcn_logf(fo1)) * LN2F;
}

extern "C" void kernel_launch(void* const* d_in, const int* in_sizes, int n_in,
                              void* d_out, int out_size, void* d_ws, size_t ws_size,
                              hipStream_t stream) {
    const float* X = (const float*)d_in[0];   // (128,128,8) f32
    const float* Y = (const float*)d_in[1];   // (16,128,8) f32
    float* out = (float*)d_out;               // (128,16) f32
    sdtw_kernel<<<512, 256, 0, stream>>>(X, Y, out);
}